// Round 8
// baseline (80.637 us; speedup 1.0000x reference)
//
#include <hip/hip_runtime.h>
#include <hip/hip_bf16.h>

#define NSTATES 8
#define HD      1024
#define NBATCH  16384
#define NT      16      // K-tiles of 64

// output layout (flat fp32, return order)
#define OUT_MEAS 0
#define OUT_CP   16777216
#define OUT_ENT  16777224
#define OUT_COH  16777225
#define OUT_AD   16777226
#define OUT_PH   16785418

typedef __attribute__((ext_vector_type(8))) short short8;
typedef __attribute__((ext_vector_type(4))) float f32x4;

__device__ __forceinline__ short f2bf(float f) {
    union { float f; unsigned u; } x; x.f = f;
    unsigned r = x.u + 0x7fffu + ((x.u >> 16) & 1u);  // RNE
    return (short)(r >> 16);
}

__device__ __forceinline__ short8 pack8(float4 a, float4 b) {
    short8 v;
    v[0] = f2bf(a.x); v[1] = f2bf(a.y); v[2] = f2bf(a.z); v[3] = f2bf(a.w);
    v[4] = f2bf(b.x); v[5] = f2bf(b.y); v[6] = f2bf(b.z); v[7] = f2bf(b.w);
    return v;
}

// ---------------- K1: amplitude pipeline (1 block, 1024 threads) ----------------
__global__ __launch_bounds__(1024) void k_amps(const float* __restrict__ AR,
                                               const float* __restrict__ AI,
                                               const float* __restrict__ H,
                                               float* __restrict__ out,
                                               float* __restrict__ w) {
    __shared__ float redA[16 * NSTATES];
    __shared__ float redB[16 * 10];
    __shared__ float norms[NSTATES];
    __shared__ float sA[8][8], sA2[8][8], sA3[8][8];
    __shared__ float Ur[8][8], Ui[8][8];
    __shared__ float lamsa[2];

    const int tid = threadIdx.x;
    const int lane = tid & 63, wid = tid >> 6;
    const int d = tid;

    float arv[NSTATES], aiv[NSTATES];
    #pragma unroll
    for (int s = 0; s < NSTATES; s++) {
        arv[s] = AR[s * HD + d];
        aiv[s] = AI[s * HD + d];
    }
    float p[NSTATES];
    #pragma unroll
    for (int s = 0; s < NSTATES; s++) p[s] = arv[s] * arv[s] + aiv[s] * aiv[s];
    #pragma unroll
    for (int s = 0; s < NSTATES; s++)
        #pragma unroll
        for (int o = 32; o > 0; o >>= 1) p[s] += __shfl_down(p[s], o, 64);
    if (lane == 0)
        #pragma unroll
        for (int s = 0; s < NSTATES; s++) redA[wid * NSTATES + s] = p[s];
    if (tid < 64) {
        int i = tid >> 3, j = tid & 7;
        sA[i][j] = 0.5f * (H[i * 8 + j] + H[j * 8 + i]) * 0.01f;  // DT/PLANCK
    }
    __syncthreads();
    if (tid < 8) {
        float acc = 0.f;
        #pragma unroll
        for (int v = 0; v < 16; v++) acc += redA[v * NSTATES + tid];
        norms[tid] = acc;
    }
    if (tid < 64) {
        int i = tid >> 3, j = tid & 7;
        float acc = 0.f;
        #pragma unroll
        for (int k = 0; k < 8; k++) acc += sA[i][k] * sA[k][j];
        sA2[i][j] = acc;
    }
    __syncthreads();
    if (tid < 64) {
        int i = tid >> 3, j = tid & 7;
        float acc = 0.f;
        #pragma unroll
        for (int k = 0; k < 8; k++) acc += sA2[i][k] * sA[k][j];
        sA3[i][j] = acc;
        Ur[i][j] = ((i == j) ? 1.f : 0.f) - 0.5f * sA2[i][j];   // cos(A)
        Ui[i][j] = -(sA[i][j] - sA3[i][j] * (1.f / 6.f));       // -sin(A)
    }
    __syncthreads();

    #pragma unroll
    for (int s = 0; s < NSTATES; s++) {
        float inv = 1.0f / sqrtf(norms[s] + 1e-8f);
        arv[s] *= inv;
        aiv[s] *= inv;
    }
    float nr[NSTATES], ni[NSTATES];
    #pragma unroll
    for (int s = 0; s < NSTATES; s++) {
        float xr = 0.f, xi = 0.f;
        #pragma unroll
        for (int t = 0; t < NSTATES; t++) {
            float ur = Ur[s][t], ui = Ui[s][t];
            xr += ur * arv[t] - ui * aiv[t];
            xi += ur * aiv[t] + ui * arv[t];
        }
        nr[s] = xr; ni[s] = xi;
    }
    float dist[NSTATES], csum = 0.f, sabs = 0.f;
    #pragma unroll
    for (int s = 0; s < NSTATES; s++) {
        dist[s] = nr[s] * nr[s] + ni[s] * ni[s];
        csum += dist[s];
        sabs += sqrtf(dist[s]);
    }
    #pragma unroll
    for (int s = 0; s < NSTATES; s++) {
        out[OUT_AD + s * HD + d] = dist[s];
        out[OUT_PH + s * HD + d] = atan2f(ni[s], nr[s]);
        w[s * HD + d] = nr[s];
    }
    float cinv = 1.0f / (csum + 1e-8f);
    float q[10];
    #pragma unroll
    for (int s = 0; s < NSTATES; s++) q[s] = dist[s] * cinv;
    q[8] = csum; q[9] = sabs;
    #pragma unroll
    for (int v = 0; v < 10; v++)
        #pragma unroll
        for (int o = 32; o > 0; o >>= 1) q[v] += __shfl_down(q[v], o, 64);
    if (lane == 0)
        #pragma unroll
        for (int v = 0; v < 10; v++) redB[wid * 10 + v] = q[v];
    __syncthreads();
    if (tid < 10) {
        float acc = 0.f;
        #pragma unroll
        for (int v = 0; v < 16; v++) acc += redB[v * 10 + tid];
        if (tid < 8)       out[OUT_CP + tid] = acc * (1.0f / HD);
        else               lamsa[tid - 8] = acc;
    }
    __syncthreads();
    if (tid == 0) {
        float lam = lamsa[0], sa = lamsa[1];
        out[OUT_ENT] = -(lam * logf(lam + 1e-12f));
        out[OUT_COH] = sa * sa - lam;
    }
}

// ---- K2: fused pre-pass. Blocks [0,256): Mt[e,d] = bf16(sum_s w[s,e]*P[s,d,e]);
// ----                     blocks [256, 8448): Xb = bf16(X) vectorized.
__global__ __launch_bounds__(256) void k_pre(const float* __restrict__ X,
                                             short* __restrict__ Xb,
                                             const float* __restrict__ P,
                                             const float* __restrict__ w,
                                             short* __restrict__ Mt) {
    __shared__ float tile[64][65];
    if (blockIdx.x >= 256) {
        int idx = (blockIdx.x - 256) * 256 + threadIdx.x;   // chunk of 8 elems
        const float* src = X + (size_t)idx * 8;
        float4 f0 = *reinterpret_cast<const float4*>(src);
        float4 f1 = *reinterpret_cast<const float4*>(src + 4);
        *reinterpret_cast<short8*>(Xb + (size_t)idx * 8) = pack8(f0, f1);
        return;
    }
    int d0 = (blockIdx.x >> 4) * 64;
    int e0 = (blockIdx.x & 15) * 64;
    int tx = threadIdx.x & 63, ty = threadIdx.x >> 6;
    float wv[NSTATES];
    #pragma unroll
    for (int s = 0; s < NSTATES; s++) wv[s] = w[s * HD + e0 + tx];
    #pragma unroll
    for (int j = 0; j < 16; j++) {
        int r = ty + 4 * j;
        float acc = 0.f;
        #pragma unroll
        for (int s = 0; s < NSTATES; s++)
            acc += wv[s] * P[(size_t)s * HD * HD + (size_t)(d0 + r) * HD + e0 + tx];
        tile[r][tx] = acc;
    }
    __syncthreads();
    #pragma unroll
    for (int j = 0; j < 16; j++) {
        int er = ty + 4 * j;
        Mt[(size_t)(e0 + er) * HD + d0 + tx] = f2bf(tile[tx][er]);
    }
}

// ---------------- K4: out = Xb @ Mt^T  -- 128^2 tile, 2 blocks/CU --------------
// 256 threads = 4 waves (2x2 per 64x64 quadrant). Same dephased quadrant-phase
// schedule as round 7 but halved tile -> 64 KiB LDS -> 2 resident blocks/CU:
// barriers sync only 4 waves, the co-resident block fills DMA/barrier bubbles
// and store tails. 4 barriers/tile (tile-end barrier merged into ph4 MID:
// ph4's MFMA reads persisted regs only; a wave issuing ph1(t+1) stages has
// passed ph4-MID => all waves' lgkm-gated reads of the overwritten slot done).

__device__ __forceinline__ void stage_half(const short* __restrict__ srcBase,
                                           int rowbase, int h, int t2,
                                           short* dst, const int* goff,
                                           const int* ldsoff) {
    #pragma unroll
    for (int i = 0; i < 2; i++) {
        const short* g = srcBase + (size_t)(rowbase + h * 64) * HD + t2 * 64 + goff[i];
        __builtin_amdgcn_global_load_lds(
            (const __attribute__((address_space(1))) void*)g,
            (__attribute__((address_space(3))) void*)(dst + h * 4096 + ldsoff[i]),
            16, 0, 0);
    }
}

#define LOAD_A(qa)                                                             \
    _Pragma("unroll") for (int mf = 0; mf < 2; mf++)                           \
    _Pragma("unroll") for (int kk = 0; kk < 2; kk++)                           \
        af[mf][kk] = *reinterpret_cast<const short8*>(                         \
            &Acur[((qa) * 64 + wr32 + mf * 16 + ln15) * 64 + kx[kk]]);

#define LOAD_B_TO(dst, qb)                                                     \
    _Pragma("unroll") for (int nf = 0; nf < 2; nf++)                           \
    _Pragma("unroll") for (int kk = 0; kk < 2; kk++)                           \
        dst[nf][kk] = *reinterpret_cast<const short8*>(                        \
            &Bcur[((qb) * 64 + wn32 + nf * 16 + ln15) * 64 + kx[kk]]);

#define MFMA_P(qa, qb, breg)                                                   \
    _Pragma("unroll") for (int mf = 0; mf < 2; mf++)                           \
    _Pragma("unroll") for (int nf = 0; nf < 2; nf++)                           \
    _Pragma("unroll") for (int kk = 0; kk < 2; kk++)                           \
        acc[(qa) * 2 + mf][(qb) * 2 + nf] =                                    \
            __builtin_amdgcn_mfma_f32_16x16x32_bf16(                           \
                af[mf][kk], breg[nf][kk], acc[(qa) * 2 + mf][(qb) * 2 + nf], 0, 0, 0);

__global__ __launch_bounds__(256, 2) void k_gemm_2b(const short* __restrict__ Xb,
                                                    const short* __restrict__ Mt,
                                                    float* __restrict__ out) {
    __shared__ short As[2][128 * 64];   // 32 KiB: [buf][half*64+row][kchunk]
    __shared__ short Bs[2][128 * 64];   // 32 KiB

    const int bid = blockIdx.x;                       // 1024 blocks (128 bm x 8 bn)
    const int swz = (bid & 7) * 128 + (bid >> 3);     // XCD-contiguous, bijective
    const int brow = (swz >> 3) * 128;
    const int bcol = (swz & 7) * 128;

    const int tid  = threadIdx.x;
    const int lane = tid & 63, wid = tid >> 6;
    const int wr = wid >> 1, wn = wid & 1;            // 2x2 waves per quadrant
    const int ln15 = lane & 15, l16 = lane >> 4;
    const int wr32 = wr * 32;
    const int wn32 = wn * 32;

    // ds_read swizzled k-chunk offsets (shorts): chunk = kg ^ (row&7); row&7==ln15&7
    int kx[2];
    kx[0] = ((l16 + 0) ^ (ln15 & 7)) * 8;
    kx[1] = ((l16 + 4) ^ (ln15 & 7)) * 8;

    // staging offsets (elements): LDS linear dest, inverse-swizzled global source
    // half-tile = 64 rows x 64 k x 2B = 8 KiB = 256 thr x 2 chunks x 16B
    int goff[2], ldsoff[2];
    #pragma unroll
    for (int i = 0; i < 2; i++) {
        int c = tid + 256 * i;
        int row = c >> 3, kc = c & 7;
        goff[i]   = row * HD + ((kc ^ (row & 7)) * 8);
        ldsoff[i] = c * 8;
    }

    short* A0 = &As[0][0]; short* A1b = &As[1][0];
    short* B0 = &Bs[0][0]; short* B1b = &Bs[1][0];

    f32x4 acc[4][4];
    #pragma unroll
    for (int m = 0; m < 4; m++)
        #pragma unroll
        for (int n = 0; n < 4; n++) acc[m][n] = (f32x4){0.f, 0.f, 0.f, 0.f};

    // prologue: tile0 (4 halves, 8 loads) + A-lo(1) + B-hi(1)  [12 loads]
    stage_half(Xb, brow, 0, 0, A0, goff, ldsoff);
    stage_half(Xb, brow, 1, 0, A0, goff, ldsoff);
    stage_half(Mt, bcol, 0, 0, B0, goff, ldsoff);
    stage_half(Mt, bcol, 1, 0, B0, goff, ldsoff);
    stage_half(Xb, brow, 0, 1, A1b, goff, ldsoff);
    stage_half(Mt, bcol, 1, 1, B1b, goff, ldsoff);
    asm volatile("s_waitcnt vmcnt(4)" ::: "memory");  // tile0's 8 loads landed
    __builtin_amdgcn_s_barrier();

    short8 af[2][2], bfL[2][2], bfH[2][2];

    #pragma unroll 1
    for (int t = 0; t < NT; t++) {
        const int cur = t & 1;
        short* Acur  = cur ? A1b : A0;
        short* Bcur  = cur ? B1b : B0;
        short* Anext = cur ? A0 : A1b;   // buf of t+1
        short* Bnext = cur ? B0 : B1b;

        // ---- ph1: quadrant (0,0); stage A-hi(t+1)
        LOAD_A(0); LOAD_B_TO(bfL, 0);
        if (t + 1 < NT) stage_half(Xb, brow, 1, t + 1, Anext, goff, ldsoff);
        __builtin_amdgcn_s_barrier();
        __builtin_amdgcn_s_setprio(1);
        MFMA_P(0, 0, bfL);
        __builtin_amdgcn_s_setprio(0);

        // ---- ph2: quadrant (0,1); stage B-lo(t+1)
        LOAD_B_TO(bfH, 1);
        if (t + 1 < NT) stage_half(Mt, bcol, 0, t + 1, Bnext, goff, ldsoff);
        __builtin_amdgcn_s_barrier();
        __builtin_amdgcn_s_setprio(1);
        MFMA_P(0, 1, bfH);
        __builtin_amdgcn_s_setprio(0);

        // ---- ph3: quadrant (1,1); stage A-lo(t+2) into cur freed slot
        LOAD_A(1);
        if (t + 2 < NT) stage_half(Xb, brow, 0, t + 2, Acur, goff, ldsoff);
        __builtin_amdgcn_s_barrier();
        __builtin_amdgcn_s_setprio(1);
        MFMA_P(1, 1, bfH);
        __builtin_amdgcn_s_setprio(0);

        // ---- ph4: quadrant (1,0) [read-free: bfL persists]; stage B-hi(t+2)
        if (t + 2 < NT) stage_half(Mt, bcol, 1, t + 2, Bcur, goff, ldsoff);
        // counted wait BEFORE the MID barrier (replaces the tile-end barrier):
        // outstanding 8 = {A-hi(t+1),B-lo(t+1),A-lo(t+2),B-hi(t+2)}; oldest 4
        // done => tile t+1 fully resident (A-lo(t+1)/B-hi(t+1) are older still).
        if (t + 2 < NT)      asm volatile("s_waitcnt vmcnt(4)" ::: "memory");
        else if (t + 1 < NT) asm volatile("s_waitcnt vmcnt(0)" ::: "memory");
        __builtin_amdgcn_s_barrier();
        __builtin_amdgcn_s_setprio(1);
        MFMA_P(1, 0, bfL);
        __builtin_amdgcn_s_setprio(0);
    }

    // epilogue: C/D layout col=lane&15, row=(lane>>4)*4+j  [m89-verified]
    #pragma unroll
    for (int qa = 0; qa < 2; qa++)
        #pragma unroll
        for (int mf = 0; mf < 2; mf++)
            #pragma unroll
            for (int qb = 0; qb < 2; qb++)
                #pragma unroll
                for (int nf = 0; nf < 2; nf++)
                    #pragma unroll
                    for (int j = 0; j < 4; j++) {
                        int r = brow + qa * 64 + wr32 + mf * 16 + l16 * 4 + j;
                        int c = bcol + qb * 64 + wn32 + nf * 16 + ln15;
                        out[(size_t)r * HD + c] = acc[qa * 2 + mf][qb * 2 + nf][j];
                    }
}

extern "C" void kernel_launch(void* const* d_in, const int* in_sizes, int n_in,
                              void* d_out, int out_size, void* d_ws, size_t ws_size,
                              hipStream_t stream) {
    const float* X  = (const float*)d_in[0];  // [16384,1024]
    const float* AR = (const float*)d_in[1];
    const float* AI = (const float*)d_in[2];
    const float* H  = (const float*)d_in[3];
    const float* P  = (const float*)d_in[4];  // [8,1024,1024]
    float* out = (float*)d_out;

    char* ws = (char*)d_ws;
    float* w  = (float*)ws;                       // 32 KB
    short* Mt = (short*)(ws + 32768);             // 2 MB  (bf16 M^T)
    short* Xb = (short*)(ws + 32768 + 2097152);   // 32 MB (bf16 X)

    k_amps<<<1, 1024, 0, stream>>>(AR, AI, H, out, w);
    k_pre<<<256 + (NBATCH * HD) / (256 * 8), 256, 0, stream>>>(X, Xb, P, w, Mt);
    k_gemm_2b<<<(NBATCH / 128) * (HD / 128), 256, 0, stream>>>(Xb, Mt, out);
}

// Round 9
// 72.075 us; speedup vs baseline: 1.1188x; 1.1188x over previous
//
#include <hip/hip_runtime.h>
#include <hip/hip_bf16.h>

#define NSTATES 8
#define HD      1024
#define NBATCH  16384
#define NT      16      // K-tiles of 64

// output layout (flat fp32, return order)
#define OUT_MEAS 0
#define OUT_CP   16777216
#define OUT_ENT  16777224
#define OUT_COH  16777225
#define OUT_AD   16777226
#define OUT_PH   16785418

typedef __attribute__((ext_vector_type(8))) short short8;
typedef __attribute__((ext_vector_type(4))) float f32x4;

__device__ __forceinline__ short f2bf(float f) {
    union { float f; unsigned u; } x; x.f = f;
    unsigned r = x.u + 0x7fffu + ((x.u >> 16) & 1u);  // RNE
    return (short)(r >> 16);
}

__device__ __forceinline__ unsigned cvtpk(float lo, float hi) {
    unsigned r;
    asm("v_cvt_pk_bf16_f32 %0, %1, %2" : "=v"(r) : "v"(lo), "v"(hi));
    return r;
}

__device__ __forceinline__ short8 pack8pk(float4 a, float4 b) {
    union { unsigned u[4]; short8 s; } r;
    r.u[0] = cvtpk(a.x, a.y);
    r.u[1] = cvtpk(a.z, a.w);
    r.u[2] = cvtpk(b.x, b.y);
    r.u[3] = cvtpk(b.z, b.w);
    return r.s;
}

// ---------------- K1: amplitude pipeline (1 block, 1024 threads) ----------------
__global__ __launch_bounds__(1024) void k_amps(const float* __restrict__ AR,
                                               const float* __restrict__ AI,
                                               const float* __restrict__ H,
                                               float* __restrict__ out,
                                               float* __restrict__ w) {
    __shared__ float redA[16 * NSTATES];
    __shared__ float redB[16 * 10];
    __shared__ float norms[NSTATES];
    __shared__ float sA[8][8], sA2[8][8], sA3[8][8];
    __shared__ float Ur[8][8], Ui[8][8];
    __shared__ float lamsa[2];

    const int tid = threadIdx.x;
    const int lane = tid & 63, wid = tid >> 6;
    const int d = tid;

    float arv[NSTATES], aiv[NSTATES];
    #pragma unroll
    for (int s = 0; s < NSTATES; s++) {
        arv[s] = AR[s * HD + d];
        aiv[s] = AI[s * HD + d];
    }
    float p[NSTATES];
    #pragma unroll
    for (int s = 0; s < NSTATES; s++) p[s] = arv[s] * arv[s] + aiv[s] * aiv[s];
    #pragma unroll
    for (int s = 0; s < NSTATES; s++)
        #pragma unroll
        for (int o = 32; o > 0; o >>= 1) p[s] += __shfl_down(p[s], o, 64);
    if (lane == 0)
        #pragma unroll
        for (int s = 0; s < NSTATES; s++) redA[wid * NSTATES + s] = p[s];
    if (tid < 64) {
        int i = tid >> 3, j = tid & 7;
        sA[i][j] = 0.5f * (H[i * 8 + j] + H[j * 8 + i]) * 0.01f;  // DT/PLANCK
    }
    __syncthreads();
    if (tid < 8) {
        float acc = 0.f;
        #pragma unroll
        for (int v = 0; v < 16; v++) acc += redA[v * NSTATES + tid];
        norms[tid] = acc;
    }
    if (tid < 64) {
        int i = tid >> 3, j = tid & 7;
        float acc = 0.f;
        #pragma unroll
        for (int k = 0; k < 8; k++) acc += sA[i][k] * sA[k][j];
        sA2[i][j] = acc;
    }
    __syncthreads();
    if (tid < 64) {
        int i = tid >> 3, j = tid & 7;
        float acc = 0.f;
        #pragma unroll
        for (int k = 0; k < 8; k++) acc += sA2[i][k] * sA[k][j];
        sA3[i][j] = acc;
        Ur[i][j] = ((i == j) ? 1.f : 0.f) - 0.5f * sA2[i][j];   // cos(A)
        Ui[i][j] = -(sA[i][j] - sA3[i][j] * (1.f / 6.f));       // -sin(A)
    }
    __syncthreads();

    #pragma unroll
    for (int s = 0; s < NSTATES; s++) {
        float inv = 1.0f / sqrtf(norms[s] + 1e-8f);
        arv[s] *= inv;
        aiv[s] *= inv;
    }
    float nr[NSTATES], ni[NSTATES];
    #pragma unroll
    for (int s = 0; s < NSTATES; s++) {
        float xr = 0.f, xi = 0.f;
        #pragma unroll
        for (int t = 0; t < NSTATES; t++) {
            float ur = Ur[s][t], ui = Ui[s][t];
            xr += ur * arv[t] - ui * aiv[t];
            xi += ur * aiv[t] + ui * arv[t];
        }
        nr[s] = xr; ni[s] = xi;
    }
    float dist[NSTATES], csum = 0.f, sabs = 0.f;
    #pragma unroll
    for (int s = 0; s < NSTATES; s++) {
        dist[s] = nr[s] * nr[s] + ni[s] * ni[s];
        csum += dist[s];
        sabs += sqrtf(dist[s]);
    }
    #pragma unroll
    for (int s = 0; s < NSTATES; s++) {
        out[OUT_AD + s * HD + d] = dist[s];
        out[OUT_PH + s * HD + d] = atan2f(ni[s], nr[s]);
        w[s * HD + d] = nr[s];
    }
    float cinv = 1.0f / (csum + 1e-8f);
    float q[10];
    #pragma unroll
    for (int s = 0; s < NSTATES; s++) q[s] = dist[s] * cinv;
    q[8] = csum; q[9] = sabs;
    #pragma unroll
    for (int v = 0; v < 10; v++)
        #pragma unroll
        for (int o = 32; o > 0; o >>= 1) q[v] += __shfl_down(q[v], o, 64);
    if (lane == 0)
        #pragma unroll
        for (int v = 0; v < 10; v++) redB[wid * 10 + v] = q[v];
    __syncthreads();
    if (tid < 10) {
        float acc = 0.f;
        #pragma unroll
        for (int v = 0; v < 16; v++) acc += redB[v * 10 + tid];
        if (tid < 8)       out[OUT_CP + tid] = acc * (1.0f / HD);
        else               lamsa[tid - 8] = acc;
    }
    __syncthreads();
    if (tid == 0) {
        float lam = lamsa[0], sa = lamsa[1];
        out[OUT_ENT] = -(lam * logf(lam + 1e-12f));
        out[OUT_COH] = sa * sa - lam;
    }
}

// ------- K3: fused project + transpose: Mt[e,d] = bf16( sum_s w[s,e]*P[s,d,e] ) -
__global__ __launch_bounds__(256) void k_project_t(const float* __restrict__ P,
                                                   const float* __restrict__ w,
                                                   short* __restrict__ Mt) {
    __shared__ float tile[64][65];
    int d0 = (blockIdx.x >> 4) * 64;
    int e0 = (blockIdx.x & 15) * 64;
    int tx = threadIdx.x & 63, ty = threadIdx.x >> 6;
    float wv[NSTATES];
    #pragma unroll
    for (int s = 0; s < NSTATES; s++) wv[s] = w[s * HD + e0 + tx];
    #pragma unroll
    for (int j = 0; j < 16; j++) {
        int r = ty + 4 * j;
        float acc = 0.f;
        #pragma unroll
        for (int s = 0; s < NSTATES; s++)
            acc += wv[s] * P[(size_t)s * HD * HD + (size_t)(d0 + r) * HD + e0 + tx];
        tile[r][tx] = acc;
    }
    __syncthreads();
    #pragma unroll
    for (int j = 0; j < 16; j++) {
        int er = ty + 4 * j;
        Mt[(size_t)(e0 + er) * HD + d0 + tx] = f2bf(tile[tx][er]);
    }
}

// -------- K4: out = bf16(X) @ Mt^T -- 256^2 lean quadrant-phase, JIT-A ---------
// 512 threads = 8 waves (2M x 4N per 128x128 quadrant). A is JIT-cast from fp32
// X via reg window + v_cvt_pk_bf16_f32 + ds_write (2-phase issue->write lead);
// B staged by global_load_lds. One MID barrier per phase (R7-proven dephased
// schedule); B-lo frags persist ph1->ph4; A,B double-buffered (128 KiB LDS).
// Publish: the single lgkmcnt(0) at ph4 covers both A-halves' ds_writes (their
// first cross-wave reads are >=1 barrier later).

__device__ __forceinline__ void stage_half_B(const short* __restrict__ srcBase,
                                             int rowbase, int h, int t2,
                                             short* dst, const int* goff,
                                             const int* ldsoff) {
    #pragma unroll
    for (int i = 0; i < 2; i++) {
        const short* g = srcBase + (size_t)(rowbase + h * 128) * HD + t2 * 64 + goff[i];
        __builtin_amdgcn_global_load_lds(
            (const __attribute__((address_space(1))) void*)g,
            (__attribute__((address_space(3))) void*)(dst + h * 8192 + ldsoff[i]),
            16, 0, 0);
    }
}

#define XLOAD(dst, h, t2)                                                      \
    {                                                                          \
        const float* b_ = X + (size_t)(brow + (h) * 128) * HD + (t2) * 64;     \
        dst[0] = *reinterpret_cast<const float4*>(b_ + goff[0]);               \
        dst[1] = *reinterpret_cast<const float4*>(b_ + goff[0] + 4);           \
        dst[2] = *reinterpret_cast<const float4*>(b_ + goff[1]);               \
        dst[3] = *reinterpret_cast<const float4*>(b_ + goff[1] + 4);           \
    }

#define XWRITE(dstlds, src)                                                    \
    {                                                                          \
        *reinterpret_cast<short8*>((dstlds) + ldsoff[0]) = pack8pk(src[0], src[1]); \
        *reinterpret_cast<short8*>((dstlds) + ldsoff[1]) = pack8pk(src[2], src[3]); \
    }

#define LOAD_A(qa)                                                             \
    _Pragma("unroll") for (int mf = 0; mf < 4; mf++)                           \
    _Pragma("unroll") for (int kk = 0; kk < 2; kk++)                           \
        af[mf][kk] = *reinterpret_cast<const short8*>(                         \
            &Acur[((qa) * 128 + wr64 + mf * 16 + ln15) * 64 + kx[kk]]);

#define LOAD_B_TO(dst, qb)                                                     \
    _Pragma("unroll") for (int nf = 0; nf < 2; nf++)                           \
    _Pragma("unroll") for (int kk = 0; kk < 2; kk++)                           \
        dst[nf][kk] = *reinterpret_cast<const short8*>(                        \
            &Bcur[((qb) * 128 + wn32 + nf * 16 + ln15) * 64 + kx[kk]]);

#define MFMA_P(qa, qb, breg)                                                   \
    _Pragma("unroll") for (int mf = 0; mf < 4; mf++)                           \
    _Pragma("unroll") for (int nf = 0; nf < 2; nf++)                           \
    _Pragma("unroll") for (int kk = 0; kk < 2; kk++)                           \
        acc[(qa) * 4 + mf][(qb) * 2 + nf] =                                    \
            __builtin_amdgcn_mfma_f32_16x16x32_bf16(                           \
                af[mf][kk], breg[nf][kk], acc[(qa) * 4 + mf][(qb) * 2 + nf], 0, 0, 0);

__global__ __launch_bounds__(512, 1) void k_gemm_jit(const float* __restrict__ X,
                                                     const short* __restrict__ Mt,
                                                     float* __restrict__ out) {
    __shared__ short As[2][256 * 64];   // 64 KiB: [buf][half*128+row][kchunk]
    __shared__ short Bs[2][256 * 64];   // 64 KiB

    const int bid = blockIdx.x;                       // 256 blocks (64 bm x 4 bn)
    const int swz = (bid & 7) * 32 + (bid >> 3);      // XCD-contiguous, bijective
    const int brow = (swz >> 2) * 256;
    const int bcol = (swz & 3) * 256;

    const int tid  = threadIdx.x;
    const int lane = tid & 63, wid = tid >> 6;
    const int wr = wid >> 2, wn = wid & 3;
    const int ln15 = lane & 15, l16 = lane >> 4;
    const int wr64 = wr * 64;
    const int wn32 = wn * 32;

    // ds_read swizzled k-chunk offsets (shorts): chunk = kg ^ (row&7); row&7==ln15&7
    int kx[2];
    kx[0] = ((l16 + 0) ^ (ln15 & 7)) * 8;
    kx[1] = ((l16 + 4) ^ (ln15 & 7)) * 8;

    // staging offsets (elements): LDS linear dest, inverse-swizzled global source
    int goff[2], ldsoff[2];
    #pragma unroll
    for (int i = 0; i < 2; i++) {
        int c = tid + 512 * i;
        int row = c >> 3, kc = c & 7;
        goff[i]   = row * HD + ((kc ^ (row & 7)) * 8);
        ldsoff[i] = c * 8;
    }

    short* A0 = &As[0][0]; short* A1b = &As[1][0];
    short* B0 = &Bs[0][0]; short* B1b = &Bs[1][0];

    f32x4 acc[8][4];
    #pragma unroll
    for (int m = 0; m < 8; m++)
        #pragma unroll
        for (int n = 0; n < 4; n++) acc[m][n] = (f32x4){0.f, 0.f, 0.f, 0.f};

    float4 xrL[4], xrH[4];

    // ---- prologue: A(0) via reg+write; B(0) lo+hi DMA; B-hi(1) DMA ----
    XLOAD(xrL, 0, 0);
    XLOAD(xrH, 1, 0);
    stage_half_B(Mt, bcol, 0, 0, B0, goff, ldsoff);
    stage_half_B(Mt, bcol, 1, 0, B0, goff, ldsoff);
    stage_half_B(Mt, bcol, 1, 1, B1b, goff, ldsoff);
    XWRITE(A0, xrL);            // auto-waits the X loads
    XWRITE(A0 + 8192, xrH);
    // outstanding VMEM: 6 B loads; need B(0)'s 4 -> vmcnt(2); publish A writes
    asm volatile("s_waitcnt vmcnt(2) lgkmcnt(0)" ::: "memory");
    __builtin_amdgcn_s_barrier();

    short8 af[4][2], bfL[2][2], bfH[2][2];

    #pragma unroll 1
    for (int t = 0; t < NT; t++) {
        const int cur = t & 1;
        short* Acur  = cur ? A1b : A0;
        short* Bcur  = cur ? B1b : B0;
        short* Anext = cur ? A0 : A1b;   // buf of t+1
        short* Bnext = cur ? B0 : B1b;

        // ---- ph1: quadrant (0,0); issue X-lo(t+1)
        LOAD_A(0); LOAD_B_TO(bfL, 0);
        if (t + 1 < NT) XLOAD(xrL, 0, (t + 1));
        __builtin_amdgcn_s_barrier();
        __builtin_amdgcn_s_setprio(1);
        MFMA_P(0, 0, bfL);
        __builtin_amdgcn_s_setprio(0);

        // ---- ph2: quadrant (0,1); issue X-hi(t+1); DMA B-lo(t+1)
        LOAD_B_TO(bfH, 1);
        if (t + 1 < NT) {
            XLOAD(xrH, 1, (t + 1));
            stage_half_B(Mt, bcol, 0, t + 1, Bnext, goff, ldsoff);
        }
        __builtin_amdgcn_s_barrier();
        __builtin_amdgcn_s_setprio(1);
        MFMA_P(0, 1, bfH);
        __builtin_amdgcn_s_setprio(0);

        // ---- ph3: quadrant (1,1); write A-lo(t+1) (2-phase lead from ph1)
        LOAD_A(1);
        if (t + 1 < NT) XWRITE(Anext, xrL);
        __builtin_amdgcn_s_barrier();
        __builtin_amdgcn_s_setprio(1);
        MFMA_P(1, 1, bfH);
        __builtin_amdgcn_s_setprio(0);

        // ---- ph4: quadrant (1,0) [read-free: bfL persists];
        //      write A-hi(t+1); DMA B-hi(t+2) into cur freed slot
        if (t + 1 < NT) XWRITE(Anext + 8192, xrH);
        if (t + 2 < NT) stage_half_B(Mt, bcol, 1, t + 2, Bcur, goff, ldsoff);
        // counted wait: xr loads auto-drained by their ds_write consumers;
        // outstanding = {B-lo(t+1):2 (ph2), B-hi(t+2):2 (just issued)} ->
        // vmcnt(2) completes all of tile t+1's B (B-hi(t+1) is older still).
        // lgkmcnt(0) publishes both A-half writes before the barrier.
        if (t + 2 < NT)      asm volatile("s_waitcnt vmcnt(2) lgkmcnt(0)" ::: "memory");
        else if (t + 1 < NT) asm volatile("s_waitcnt vmcnt(0) lgkmcnt(0)" ::: "memory");
        __builtin_amdgcn_s_barrier();
        __builtin_amdgcn_s_setprio(1);
        MFMA_P(1, 0, bfL);
        __builtin_amdgcn_s_setprio(0);
    }

    // epilogue: C/D layout col=lane&15, row=(lane>>4)*4+j  [m89-verified]
    #pragma unroll
    for (int qa = 0; qa < 2; qa++)
        #pragma unroll
        for (int mf = 0; mf < 4; mf++)
            #pragma unroll
            for (int qb = 0; qb < 2; qb++)
                #pragma unroll
                for (int nf = 0; nf < 2; nf++)
                    #pragma unroll
                    for (int j = 0; j < 4; j++) {
                        int r = brow + qa * 128 + wr64 + mf * 16 + l16 * 4 + j;
                        int c = bcol + qb * 128 + wn32 + nf * 16 + ln15;
                        out[(size_t)r * HD + c] = acc[qa * 4 + mf][qb * 2 + nf][j];
                    }
}

extern "C" void kernel_launch(void* const* d_in, const int* in_sizes, int n_in,
                              void* d_out, int out_size, void* d_ws, size_t ws_size,
                              hipStream_t stream) {
    const float* X  = (const float*)d_in[0];  // [16384,1024]
    const float* AR = (const float*)d_in[1];
    const float* AI = (const float*)d_in[2];
    const float* H  = (const float*)d_in[3];
    const float* P  = (const float*)d_in[4];  // [8,1024,1024]
    float* out = (float*)d_out;

    char* ws = (char*)d_ws;
    float* w  = (float*)ws;                       // 32 KB
    short* Mt = (short*)(ws + 32768);             // 2 MB  (bf16 M^T)

    k_amps<<<1, 1024, 0, stream>>>(AR, AI, H, out, w);
    k_project_t<<<256, 256, 0, stream>>>(P, w, Mt);
    k_gemm_jit<<<(NBATCH / 256) * (HD / 256), 512, 0, stream>>>(X, Mt, out);
}